// Round 5
// baseline (837.839 us; speedup 1.0000x reference)
//
#include <hip/hip_runtime.h>

typedef unsigned short u16;
typedef __attribute__((ext_vector_type(8))) short bf16x8;
typedef __attribute__((ext_vector_type(4))) float f32x4;

#define C_    192
#define HW_   65536
#define NWIN  4096

__device__ inline u16 f2bf(float f) {
  union { float f; unsigned u; } x; x.f = f;
  unsigned r = x.u + 0x7FFFu + ((x.u >> 16) & 1u);
  return (u16)(r >> 16);
}
__device__ inline float bf2f(u16 s) {
  union { unsigned u; float f; } x; x.u = ((unsigned)s) << 16;
  return x.f;
}
// swizzle x-life columns of R0: XOR bits 3..5 of c within its 64-block by (t>>2)&7
__device__ inline int swzc(int c, int t) {
  return (c & ~63) | ((c & 63) ^ (((t >> 2) & 7) << 3));
}

// ---------------- k0: weights fp32 -> bf16, combined qkv bias ----------------
__global__ void k_convert(const float* __restrict__ qkv_w, const float* __restrict__ proj_w,
                          const float* __restrict__ q_bias, const float* __restrict__ v_bias,
                          u16* __restrict__ wq, u16* __restrict__ wp, float* __restrict__ qkvb) {
  int i = blockIdx.x * 256 + threadIdx.x;
  if (i < 110592) wq[i] = f2bf(qkv_w[i]);
  else if (i < 147456) wp[i - 110592] = f2bf(proj_w[i - 110592]);
  else if (i < 148032) {
    int j = i - 147456;
    qkvb[j] = (j < 192) ? q_bias[j] : ((j < 384) ? 0.f : v_bias[j - 384]);
  }
}

// ---------------- k1: CPB MLP table (225 x 8) ----------------
__global__ void k_table(const float* __restrict__ w1, const float* __restrict__ b1,
                        const float* __restrict__ w2, float* __restrict__ table) {
  int row = blockIdx.x;            // 0..224
  int tid = threadIdx.x;
  int a = row / 15, b = row % 15;
  float va = (float)(a - 7) * (8.0f / 7.0f);
  float vb = (float)(b - 7) * (8.0f / 7.0f);
  float c0 = copysignf(log2f(fabsf(va) + 1.0f) * (1.0f / 3.0f), va);
  float c1 = copysignf(log2f(fabsf(vb) + 1.0f) * (1.0f / 3.0f), vb);
  float acc[8];
#pragma unroll
  for (int o = 0; o < 8; ++o) acc[o] = 0.f;
  for (int k = tid; k < 512; k += 256) {
    float h = fmaxf(c0 * w1[k] + c1 * w1[512 + k] + b1[k], 0.f);
#pragma unroll
    for (int o = 0; o < 8; ++o) acc[o] += h * w2[k * 8 + o];
  }
  __shared__ float part[4][8];
  int wave = tid >> 6;
#pragma unroll
  for (int o = 0; o < 8; ++o) {
    float v = acc[o];
    v += __shfl_xor(v, 1, 64);  v += __shfl_xor(v, 2, 64);
    v += __shfl_xor(v, 4, 64);  v += __shfl_xor(v, 8, 64);
    v += __shfl_xor(v, 16, 64); v += __shfl_xor(v, 32, 64);
    acc[o] = v;
  }
  if ((tid & 63) == 0)
#pragma unroll
    for (int o = 0; o < 8; ++o) part[wave][o] = acc[o];
  __syncthreads();
  if (tid < 8)
    table[row * 8 + tid] = part[0][tid] + part[1][tid] + part[2][tid] + part[3][tid];
}

// ---- k2: bias grid, flat = h*4096 + t*64 + g*16 + nt*4 + r;
//      value = bias[h][t][s = nt*16 + g*4 + r] ----
__global__ void k_biasfill(const float* __restrict__ table, float* __restrict__ bias3) {
  int p = blockIdx.x * 256 + threadIdx.x;   // 32768 total
  int h = p >> 12, t = (p >> 6) & 63, g = (p >> 4) & 3, u = p & 15;
  int nt = u >> 2, r = u & 3;
  int s = nt * 16 + g * 4 + r;
  int idx = ((t >> 3) - (s >> 3) + 7) * 15 + ((t & 7) - (s & 7) + 7);
  float v = table[idx * 8 + h];
  bias3[p] = 16.0f / (1.0f + __expf(-v));
}

// ---------------- main fused kernel: 1 window/block, 8 waves, 2 blocks/CU ----------------
__global__ __launch_bounds__(512, 4)
void k_main(const float* __restrict__ x,
            const float* __restrict__ ls, const float* __restrict__ proj_b,
            const u16* __restrict__ wq, const u16* __restrict__ wp,
            const float* __restrict__ qkvb, const float* __restrict__ bias3,
            float* __restrict__ out) {
  __shared__ u16 smem[38400];                 // 76,800 B -> 2 blocks/CU
  u16* R0 = smem;                             // [64][200]: x (swizzled cols), later ao (plain)
  u16* Ar = smem + 12800;                     // 24576 u16: per-head qk / P-bounce+v^T / obuf
  float* invk_s = (float*)(smem + 37376);     // [8][64]

  int tid  = threadIdx.x;
  int wave = tid >> 6, lane = tid & 63, g = lane >> 4, li = lane & 15;
  int tt = wave & 3, half = wave >> 2;
  int bid = blockIdx.x;
  int b = bid >> 10, wy = (bid >> 5) & 31, wx = bid & 31;
  const float* xb = x + (size_t)b * C_ * HW_;
  int base = (wy * 8) * 256 + wx * 8;
  bf16x8 z8 = {0, 0, 0, 0, 0, 0, 0, 0};
  f32x4 zf = {0.f, 0.f, 0.f, 0.f};

  float lsh = ls[wave];
  // prefetch q A-frag weights (12 x b128) -- independent of x, hides under P1
  bf16x8 qw[2][6];
#pragma unroll
  for (int m = 0; m < 2; ++m)
#pragma unroll
    for (int ks = 0; ks < 6; ++ks)
      qw[m][ks] = *(const bf16x8*)(wq + (wave * 24 + m * 16 + li) * 192 + ks * 32 + g * 8);

  // ---- P1: stage x -> bf16 LDS [t][swz c] ----
#pragma unroll
  for (int it = 0; it < 6; ++it) {
    int i4 = tid + it * 512;                  // 3072 tasks
    int c = i4 >> 4, rem = i4 & 15;
    int ty = rem >> 1, jj = (rem & 1) * 4;
    float4 v = *(const float4*)(xb + c * HW_ + base + ty * 256 + jj);
    int t0 = ty * 8 + jj;
    int cs = swzc(c, t0);                     // t0..t0+3 share t>>2
    R0[(t0 + 0) * 200 + cs] = f2bf(v.x);
    R0[(t0 + 1) * 200 + cs] = f2bf(v.y);
    R0[(t0 + 2) * 200 + cs] = f2bf(v.z);
    R0[(t0 + 3) * 200 + cs] = f2bf(v.w);
  }
  __syncthreads();                            // B1

  u16* Hq = Ar + wave * 3072;                 // [64][24]
  u16* Hk = Hq + 1536;                        // [64][24]
  float scaleh = __expf(fminf(lsh, 4.6051702f));
  float iqr[4];
  bf16x8 qf[4], kf[4];

  // ---- P2q: per-head q GEMM (same-wave produce/consume) + fused norm ----
  {
    f32x4 cb0 = *(const f32x4*)(qkvb + wave * 24 + g * 4);
    f32x4 cb1 = *(const f32x4*)(qkvb + wave * 24 + 16 + g * 4);  // junk g>=2, masked
#pragma unroll
    for (int tb = 0; tb < 4; ++tb) {
      int t = tb * 16 + li;
      bf16x8 xf[6];
#pragma unroll
      for (int ks = 0; ks < 6; ++ks)
        xf[ks] = *(const bf16x8*)&R0[t * 200 + swzc(ks * 32 + g * 8, t)];
      f32x4 a0 = zf, a1 = zf;
#pragma unroll
      for (int ks = 0; ks < 6; ++ks) {
        a0 = __builtin_amdgcn_mfma_f32_16x16x32_bf16(qw[0][ks], xf[ks], a0, 0, 0, 0);
        a1 = __builtin_amdgcn_mfma_f32_16x16x32_bf16(qw[1][ks], xf[ks], a1, 0, 0, 0);
      }
      float p = 0.f;
#pragma unroll
      for (int r = 0; r < 4; ++r) { a0[r] += cb0[r]; p += a0[r] * a0[r]; }
      if (g < 2) {
#pragma unroll
        for (int r = 0; r < 4; ++r) { a1[r] += cb1[r]; p += a1[r] * a1[r]; }
      }
      p += __shfl_xor(p, 16, 64);
      p += __shfl_xor(p, 32, 64);
      iqr[tb] = __builtin_amdgcn_rsqf(fmaxf(p, 1e-24f)) * scaleh;
      uint2 pk;
      pk.x = f2bf(a0[0]) | ((unsigned)f2bf(a0[1]) << 16);
      pk.y = f2bf(a0[2]) | ((unsigned)f2bf(a0[3]) << 16);
      *(uint2*)&Hq[t * 24 + g * 4] = pk;
      if (g < 2) {
        pk.x = f2bf(a1[0]) | ((unsigned)f2bf(a1[1]) << 16);
        pk.y = f2bf(a1[2]) | ((unsigned)f2bf(a1[3]) << 16);
        *(uint2*)&Hq[t * 24 + 16 + g * 4] = pk;
      }
    }
  }

  // ---- P2k: per-head k GEMM + fused norm ----
  {
    bf16x8 kw[2][6];
#pragma unroll
    for (int m = 0; m < 2; ++m)
#pragma unroll
      for (int ks = 0; ks < 6; ++ks)
        kw[m][ks] = *(const bf16x8*)(wq + (192 + wave * 24 + m * 16 + li) * 192 + ks * 32 + g * 8);
    f32x4 cb0 = *(const f32x4*)(qkvb + 192 + wave * 24 + g * 4);
    f32x4 cb1 = *(const f32x4*)(qkvb + 192 + wave * 24 + 16 + g * 4);
#pragma unroll
    for (int nt = 0; nt < 4; ++nt) {
      int t = nt * 16 + li;
      bf16x8 xf[6];
#pragma unroll
      for (int ks = 0; ks < 6; ++ks)
        xf[ks] = *(const bf16x8*)&R0[t * 200 + swzc(ks * 32 + g * 8, t)];
      f32x4 a0 = zf, a1 = zf;
#pragma unroll
      for (int ks = 0; ks < 6; ++ks) {
        a0 = __builtin_amdgcn_mfma_f32_16x16x32_bf16(kw[0][ks], xf[ks], a0, 0, 0, 0);
        a1 = __builtin_amdgcn_mfma_f32_16x16x32_bf16(kw[1][ks], xf[ks], a1, 0, 0, 0);
      }
      float p = 0.f;
#pragma unroll
      for (int r = 0; r < 4; ++r) { a0[r] += cb0[r]; p += a0[r] * a0[r]; }
      if (g < 2) {
#pragma unroll
        for (int r = 0; r < 4; ++r) { a1[r] += cb1[r]; p += a1[r] * a1[r]; }
      }
      p += __shfl_xor(p, 16, 64);
      p += __shfl_xor(p, 32, 64);
      float ik = __builtin_amdgcn_rsqf(fmaxf(p, 1e-24f));
      if (g == 0) invk_s[wave * 64 + t] = ik;
      uint2 pk;
      pk.x = f2bf(a0[0]) | ((unsigned)f2bf(a0[1]) << 16);
      pk.y = f2bf(a0[2]) | ((unsigned)f2bf(a0[3]) << 16);
      *(uint2*)&Hk[t * 24 + g * 4] = pk;
      if (g < 2) {
        pk.x = f2bf(a1[0]) | ((unsigned)f2bf(a1[1]) << 16);
        pk.y = f2bf(a1[2]) | ((unsigned)f2bf(a1[3]) << 16);
        *(uint2*)&Hk[t * 24 + 16 + g * 4] = pk;
      }
    }
  }

  // ---- hoist q/k MFMA fragments (same-wave LDS, no barrier needed) ----
#pragma unroll
  for (int tb = 0; tb < 4; ++tb) {
    qf[tb] = (g < 3) ? *(const bf16x8*)&Hq[(tb * 16 + li) * 24 + g * 8] : z8;
    kf[tb] = (g < 3) ? *(const bf16x8*)&Hk[(tb * 16 + li) * 24 + g * 8] : z8;
  }
  __syncthreads();                            // B2a (qk region dead)

  // ---- P2v: v GEMM -> v^T [192][72] (region Ar+10752) ----
  u16* vt = smem + 23552;
  {
    bf16x8 xfv[6];
#pragma unroll
    for (int ks = 0; ks < 6; ++ks)
      xfv[ks] = *(const bf16x8*)&R0[(tt * 16 + li) * 200 + swzc(ks * 32 + g * 8, tt * 16 + li)];
#pragma unroll
    for (int it = 0; it < 6; ++it) {
      int jv = half * 96 + it * 16;
      const u16* wr = wq + (384 + jv + li) * 192 + g * 8;
      f32x4 a0 = zf, a1 = zf;
#pragma unroll
      for (int ks = 0; ks < 3; ++ks) {
        bf16x8 w0 = *(const bf16x8*)(wr + ks * 32);
        bf16x8 w1 = *(const bf16x8*)(wr + (ks + 3) * 32);
        a0 = __builtin_amdgcn_mfma_f32_16x16x32_bf16(xfv[ks], w0, a0, 0, 0, 0);
        a1 = __builtin_amdgcn_mfma_f32_16x16x32_bf16(xfv[ks + 3], w1, a1, 0, 0, 0);
      }
      float cb = qkvb[384 + jv + li];
      uint2 pk;
      pk.x = f2bf(a0[0] + a1[0] + cb) | ((unsigned)f2bf(a0[1] + a1[1] + cb) << 16);
      pk.y = f2bf(a0[2] + a1[2] + cb) | ((unsigned)f2bf(a0[3] + a1[3] + cb) << 16);
      *(uint2*)&vt[(jv + li) * 72 + tt * 16 + g * 4] = pk;
    }
  }
  __syncthreads();                            // B2b (v^T visible; x dead)

  // ---- P4: attention, S^T = K.Q^T; wave = head; ao -> R0 (plain layout) ----
  {
    int h = wave;
    bf16x8 v0f[2], v1f[2];
#pragma unroll
    for (int ks = 0; ks < 2; ++ks) {
      v0f[ks] = *(const bf16x8*)&vt[(h * 24 + li) * 72 + ks * 32 + g * 8];
      v1f[ks] = (li < 8) ? *(const bf16x8*)&vt[(h * 24 + 16 + li) * 72 + ks * 32 + g * 8] : z8;
    }
    f32x4 ik4[4];
#pragma unroll
    for (int nt = 0; nt < 4; ++nt)
      ik4[nt] = *(const f32x4*)&invk_s[h * 64 + nt * 16 + g * 4];
    u16* Pw = Ar + wave * 1152;               // [16][72] per-wave bounce
#pragma unroll
    for (int tb = 0; tb < 4; ++tb) {
      const float* bp = bias3 + ((h * 64 + tb * 16 + li) << 6) + (g << 4);
      f32x4 bx[4];
#pragma unroll
      for (int nt = 0; nt < 4; ++nt) bx[nt] = *(const f32x4*)(bp + (nt << 2));
      f32x4 s4[4];
#pragma unroll
      for (int nt = 0; nt < 4; ++nt)
        s4[nt] = __builtin_amdgcn_mfma_f32_16x16x32_bf16(kf[nt], qf[tb], zf, 0, 0, 0);
      float iq = iqr[tb];
#pragma unroll
      for (int nt = 0; nt < 4; ++nt)
#pragma unroll
        for (int r = 0; r < 4; ++r)
          s4[nt][r] = s4[nt][r] * iq * ik4[nt][r] + bx[nt][r];
      // softmax over s: 16 local + 2 shfl
      float m = s4[0][0];
#pragma unroll
      for (int nt = 0; nt < 4; ++nt)
#pragma unroll
        for (int r = 0; r < 4; ++r) m = fmaxf(m, s4[nt][r]);
      m = fmaxf(m, __shfl_xor(m, 16, 64));
      m = fmaxf(m, __shfl_xor(m, 32, 64));
      float sum = 0.f;
#pragma unroll
      for (int nt = 0; nt < 4; ++nt)
#pragma unroll
        for (int r = 0; r < 4; ++r) { float e = __expf(s4[nt][r] - m); s4[nt][r] = e; sum += e; }
      sum += __shfl_xor(sum, 16, 64);
      sum += __shfl_xor(sum, 32, 64);
      float is = __builtin_amdgcn_rcpf(sum);
      // P bounce: [t=li][s] b64 stores (unnormalized; 1/sum folded into O)
#pragma unroll
      for (int nt = 0; nt < 4; ++nt) {
        uint2 pk;
        pk.x = f2bf(s4[nt][0]) | ((unsigned)f2bf(s4[nt][1]) << 16);
        pk.y = f2bf(s4[nt][2]) | ((unsigned)f2bf(s4[nt][3]) << 16);
        *(uint2*)&Pw[li * 72 + nt * 16 + g * 4] = pk;
      }
      // PV: O^T = V^T . P^T
      f32x4 o0 = zf, o1 = zf;
#pragma unroll
      for (int ks = 0; ks < 2; ++ks) {
        bf16x8 pf = *(const bf16x8*)&Pw[li * 72 + ks * 32 + g * 8];
        o0 = __builtin_amdgcn_mfma_f32_16x16x32_bf16(v0f[ks], pf, o0, 0, 0, 0);
        o1 = __builtin_amdgcn_mfma_f32_16x16x32_bf16(v1f[ks], pf, o1, 0, 0, 0);
      }
      int t = tb * 16 + li;
      {
        uint2 pk;
        pk.x = f2bf(o0[0] * is) | ((unsigned)f2bf(o0[1] * is) << 16);
        pk.y = f2bf(o0[2] * is) | ((unsigned)f2bf(o0[3] * is) << 16);
        *(uint2*)&R0[t * 200 + h * 24 + g * 4] = pk;
      }
      if (g < 2) {
        uint2 pk;
        pk.x = f2bf(o1[0] * is) | ((unsigned)f2bf(o1[1] * is) << 16);
        pk.y = f2bf(o1[2] * is) | ((unsigned)f2bf(o1[3] * is) << 16);
        *(uint2*)&R0[t * 200 + h * 24 + 16 + g * 4] = pk;
      }
    }
  }
  __syncthreads();                            // B3 (ao ready)

  // ---- P5: proj, O = ao . Wp^T -> obuf bf16 [192][68] (b64 stores) ----
  {
    bf16x8 af[6];
#pragma unroll
    for (int ks = 0; ks < 6; ++ks)
      af[ks] = *(const bf16x8*)&R0[(tt * 16 + li) * 200 + ks * 32 + g * 8];
    u16* obuf = Ar;
#pragma unroll
    for (int it = 0; it < 6; ++it) {
      int ct = half * 96 + it * 16;
      const u16* wr = wp + (ct + li) * 192 + g * 8;
      f32x4 a0 = zf, a1 = zf;
#pragma unroll
      for (int ks = 0; ks < 3; ++ks) {
        bf16x8 w0 = *(const bf16x8*)(wr + ks * 32);
        bf16x8 w1 = *(const bf16x8*)(wr + (ks + 3) * 32);
        a0 = __builtin_amdgcn_mfma_f32_16x16x32_bf16(af[ks], w0, a0, 0, 0, 0);
        a1 = __builtin_amdgcn_mfma_f32_16x16x32_bf16(af[ks + 3], w1, a1, 0, 0, 0);
      }
      float pb = proj_b[ct + li];
      // C rows = 4 consecutive tokens tt*16+g*4+r, col = channel ct+li
      uint2 pk;
      pk.x = f2bf(a0[0] + a1[0] + pb) | ((unsigned)f2bf(a0[1] + a1[1] + pb) << 16);
      pk.y = f2bf(a0[2] + a1[2] + pb) | ((unsigned)f2bf(a0[3] + a1[3] + pb) << 16);
      *(uint2*)&obuf[(ct + li) * 68 + tt * 16 + g * 4] = pk;
    }
  }
  __syncthreads();                            // B4

  // ---- P6: residual (x re-read, L3-resident) + b64 obuf reads + store ----
  float* ob = out + (size_t)b * C_ * HW_;
  float4 xv[6];
#pragma unroll
  for (int it = 0; it < 6; ++it) {
    int i4 = tid + it * 512;
    int c = i4 >> 4, rem = i4 & 15;
    int ty = rem >> 1, jj = (rem & 1) * 4;
    xv[it] = *(const float4*)(xb + c * HW_ + base + ty * 256 + jj);
  }
  uint2 ov[6];
#pragma unroll
  for (int it = 0; it < 6; ++it) {
    int i4 = tid + it * 512;
    int c = i4 >> 4, rem = i4 & 15;
    int ty = rem >> 1, jj = (rem & 1) * 4;
    ov[it] = *(const uint2*)&Ar[c * 68 + ty * 8 + jj];
  }
#pragma unroll
  for (int it = 0; it < 6; ++it) {
    int i4 = tid + it * 512;
    int c = i4 >> 4, rem = i4 & 15;
    int ty = rem >> 1, jj = (rem & 1) * 4;
    float4 r;
    r.x = xv[it].x + bf2f((u16)(ov[it].x & 0xFFFFu));
    r.y = xv[it].y + bf2f((u16)(ov[it].x >> 16));
    r.z = xv[it].z + bf2f((u16)(ov[it].y & 0xFFFFu));
    r.w = xv[it].w + bf2f((u16)(ov[it].y >> 16));
    *(float4*)(ob + c * HW_ + base + ty * 256 + jj) = r;
  }
}

// ---------------- launcher ----------------
extern "C" void kernel_launch(void* const* d_in, const int* in_sizes, int n_in,
                              void* d_out, int out_size, void* d_ws, size_t ws_size,
                              hipStream_t stream) {
  const float* x      = (const float*)d_in[0];
  const float* qkv_w  = (const float*)d_in[2];
  const float* q_bias = (const float*)d_in[3];
  const float* v_bias = (const float*)d_in[4];
  const float* ls     = (const float*)d_in[5];
  const float* w1     = (const float*)d_in[6];
  const float* b1     = (const float*)d_in[7];
  const float* w2     = (const float*)d_in[8];
  const float* proj_w = (const float*)d_in[9];
  const float* proj_b = (const float*)d_in[10];

  u16*   wq    = (u16*)d_ws;                               // 110592 bf16
  u16*   wpv   = wq + 110592;                              // 36864 bf16 -> byte 294912
  float* qkvb  = (float*)((char*)d_ws + 294912);           // 576 f32   -> 297216
  float* bias3 = (float*)((char*)d_ws + 297216);           // 32768 f32 -> 428288
  float* table = (float*)((char*)d_ws + 428288);           // 1800 f32
  float* out   = (float*)d_out;

  hipLaunchKernelGGL(k_convert, dim3(579), dim3(256), 0, stream,
                     qkv_w, proj_w, q_bias, v_bias, wq, wpv, qkvb);
  hipLaunchKernelGGL(k_table, dim3(225), dim3(256), 0, stream, w1, b1, w2, table);
  hipLaunchKernelGGL(k_biasfill, dim3(128), dim3(256), 0, stream, table, bias3);
  hipLaunchKernelGGL(k_main, dim3(NWIN), dim3(512), 0, stream,
                     x, ls, proj_b, wq, wpv, qkvb, bias3, out);
}